// Round 3
// baseline (1174.918 us; speedup 1.0000x reference)
//
#include <hip/hip_runtime.h>
#include <hip/hip_bf16.h>

typedef _Float16 f16;
typedef f16 f16x2 __attribute__((ext_vector_type(2)));
typedef f16 f16x8 __attribute__((ext_vector_type(8)));
typedef float f32x4 __attribute__((ext_vector_type(4)));

__device__ __forceinline__ float dot2acc(f16x2 a, f16x2 b, float c) {
    return __builtin_amdgcn_fdot2(a, b, c, false);
}
__device__ __forceinline__ float sigmoid_f(float x) {
    return __builtin_amdgcn_rcpf(1.f + __expf(-x));
}
__device__ __forceinline__ float tanh_f(float x) {
    return 1.f - 2.f * __builtin_amdgcn_rcpf(__expf(2.f * x) + 1.f);
}

// ------------------------------------------------- fused weight f32->f16 convert
// Segments (vec4 units): Wp 8192 | Wih_a 49152 | Whh_a 49152 | Wih_b 49152 |
//                        Whh_b 49152 | Wb 16384  => total 221248
__global__ __launch_bounds__(256) void cvt_weights_kernel(
    const float* __restrict__ wp, const float* __restrict__ wia, const float* __restrict__ wha,
    const float* __restrict__ wib, const float* __restrict__ whb, const float* __restrict__ wb,
    f16* __restrict__ o_wp, f16* __restrict__ o_wia, f16* __restrict__ o_wha,
    f16* __restrict__ o_wib, f16* __restrict__ o_whb, f16* __restrict__ o_wb)
{
    int i = blockIdx.x * 256 + threadIdx.x;
    if (i >= 221248) return;
    const float* s; f16* d; int off;
    if      (i < 8192)   { s = wp;  d = o_wp;  off = i; }
    else if (i < 57344)  { s = wia; d = o_wia; off = i - 8192; }
    else if (i < 106496) { s = wha; d = o_wha; off = i - 57344; }
    else if (i < 155648) { s = wib; d = o_wib; off = i - 106496; }
    else if (i < 204800) { s = whb; d = o_whb; off = i - 155648; }
    else                 { s = wb;  d = o_wb;  off = i - 204800; }
    float4 f = ((const float4*)s)[off];
    f16x2 p0; p0.x = (f16)f.x; p0.y = (f16)f.y;
    f16x2 p1; p1.x = (f16)f.z; p1.y = (f16)f.w;
    ((f16x2*)d)[off * 2]     = p0;
    ((f16x2*)d)[off * 2 + 1] = p1;
}

// ---------------------------------------------------------------- MFMA GEMM
// C[M,NOUT] = A[M,KT] @ B[NOUT,KT]^T + bias, tile 128x128, BK=64, 4 waves.
// CVTA: A is fp32, converted to f16 during LDS staging.
// Bias: col < BSPLIT -> bias[col], else bias2[col-BSPLIT].
// EPI 0/1: out16 = val (f16). EPI 2: out16 = tanh(val) * xp16 (f16 "v").
#define BM 128
#define BN 128
#define BKC 64
#define LPAD 8

template <int KT, int NOUT, int EPI, bool CVTA, int BSPLIT>
__global__ __launch_bounds__(256) void gemm_kernel(
    const void* __restrict__ Araw, const f16* __restrict__ B,
    const float* __restrict__ bias, const float* __restrict__ bias2,
    f16* __restrict__ out16, const f16* __restrict__ xp16)
{
    __shared__ __align__(16) f16 As[BM][BKC + LPAD];
    __shared__ __align__(16) f16 Bs[BN][BKC + LPAD];
    int tid = threadIdx.x;
    int m0 = blockIdx.x * BM, n0 = blockIdx.y * BN;
    int wave = tid >> 6, lane = tid & 63;
    int wm = (wave & 1) * 64, wn = (wave >> 1) * 64;
    int quad = lane >> 4, l16 = lane & 15;

    f32x4 acc[4][4] = {};

    for (int kc = 0; kc < KT / BKC; ++kc) {
        __syncthreads();
#pragma unroll
        for (int i = 0; i < 4; ++i) {
            int idx = i * 256 + tid;
            int row = idx >> 3, c8 = idx & 7;
            if (CVTA) {
                const float* A32 = (const float*)Araw;
                const float* src = A32 + (size_t)(m0 + row) * KT + kc * BKC + c8 * 8;
                float4 fa = *(const float4*)src;
                float4 fb = *(const float4*)(src + 4);
                f16x8 h8;
                h8[0] = (f16)fa.x; h8[1] = (f16)fa.y; h8[2] = (f16)fa.z; h8[3] = (f16)fa.w;
                h8[4] = (f16)fb.x; h8[5] = (f16)fb.y; h8[6] = (f16)fb.z; h8[7] = (f16)fb.w;
                *(f16x8*)&As[row][c8 * 8] = h8;
            } else {
                const f16* A16 = (const f16*)Araw;
                uint4 va = *(const uint4*)(A16 + (size_t)(m0 + row) * KT + kc * BKC + c8 * 8);
                *(uint4*)&As[row][c8 * 8] = va;
            }
            uint4 vb = *(const uint4*)(B + (size_t)(n0 + row) * KT + kc * BKC + c8 * 8);
            *(uint4*)&Bs[row][c8 * 8] = vb;
        }
        __syncthreads();
#pragma unroll
        for (int kk = 0; kk < 2; ++kk) {
            f16x8 af[4], bf[4];
#pragma unroll
            for (int i = 0; i < 4; ++i) {
                af[i] = *(const f16x8*)&As[wm + i * 16 + l16][kk * 32 + quad * 8];
                bf[i] = *(const f16x8*)&Bs[wn + i * 16 + l16][kk * 32 + quad * 8];
            }
#pragma unroll
            for (int mi = 0; mi < 4; ++mi)
#pragma unroll
                for (int ni = 0; ni < 4; ++ni)
                    acc[mi][ni] = __builtin_amdgcn_mfma_f32_16x16x32_f16(af[mi], bf[ni], acc[mi][ni], 0, 0, 0);
        }
    }

#pragma unroll
    for (int ni = 0; ni < 4; ++ni) {
        int col = n0 + wn + ni * 16 + l16;
        float bv = (col < BSPLIT) ? bias[col] : bias2[col - BSPLIT];
#pragma unroll
        for (int mi = 0; mi < 4; ++mi) {
#pragma unroll
            for (int r = 0; r < 4; ++r) {
                int row = m0 + wm + mi * 16 + quad * 4 + r;
                float val = acc[mi][ni][r] + bv;
                if (EPI == 2) {
                    float tb = tanh_f(val);
                    float xpv = (float)xp16[(size_t)row * NOUT + col];
                    out16[(size_t)row * NOUT + col] = (f16)(tb * xpv);
                } else {
                    out16[(size_t)row * NOUT + col] = (f16)val;
                }
            }
        }
    }
}

// ---------------------------------------------------------------- GRU recurrence
// 256 blocks: blockIdx>>7 selects GRU (0=a,1=b), &127 selects batch element.
// 768 threads, k-split dot: thread t = (j0 = t>>2, q = t&3).
//   - holds Whh row-quarters for outputs {j0+192i, i=0..3} over h-chunk q (128 f16x2 VGPRs)
//   - reads only chunk q of h from LDS: 8 ds_read_b128/step (chunks padded to 144 B
//     so the 4 concurrent chunk addresses hit disjoint banks)
//   - quad butterfly (shfl_xor 1,2) reduces the 4 partials; lane q writes output j0+192q.
// GRU a fuses scores = h . Wa (xa never materialized); GRU b writes h f16 into d_out.
#define XWS 1536

__global__ __launch_bounds__(768, 3) void rnn_kernel(
    const f16* __restrict__ xw_cat,
    const f16* __restrict__ whha, const f16* __restrict__ whhb,
    const float* __restrict__ bhha, const float* __restrict__ bhhb,
    const float* __restrict__ Wa,
    f16* __restrict__ xb16, float* __restrict__ scores)
{
    int g = blockIdx.x >> 7, b = blockIdx.x & 127;
    int t = threadIdx.x;
    int q = t & 3, j0 = t >> 2;          // k-chunk, output group
    int mout = j0 + 192 * q;             // the output this lane writes

    const f16* whh = g ? whhb : whha;
    const float* bhh = g ? bhhb : bhha;
    const f16* xw = xw_cat + (size_t)b * 512 * XWS + 768 * g;

    // weights: 4 outputs x 32 f16x2 (h-chunk q) = 128 VGPRs
    f16x2 w[128];
#pragma unroll
    for (int i = 0; i < 4; ++i) {
        const f16* src = whh + (size_t)(j0 + 192 * i) * 256 + q * 64;
#pragma unroll
        for (int b8 = 0; b8 < 8; ++b8) {
            uint4 u = *(const uint4*)(src + b8 * 8);
            w[i * 32 + b8 * 4 + 0] = __builtin_bit_cast(f16x2, u.x);
            w[i * 32 + b8 * 4 + 1] = __builtin_bit_cast(f16x2, u.y);
            w[i * 32 + b8 * 4 + 2] = __builtin_bit_cast(f16x2, u.z);
            w[i * 32 + b8 * 4 + 3] = __builtin_bit_cast(f16x2, u.w);
        }
    }
    float bregq = bhh[mout];
    float waj = (t < 256) ? Wa[t] : 0.f;

    // h chunks padded: chunk c at f16x2 offset c*36 (144 B stride -> disjoint banks)
    __shared__ __align__(16) f16x2 h2[2][144];
    __shared__ float hw[768];
    __shared__ float spart[4];

    if (t < 144) { h2[0][t] = __builtin_bit_cast(f16x2, 0u); }
    __syncthreads();

    float hprev = 0.f;
    int cur = 0;
    for (int ts = 0; ts < 512; ++ts) {
        float xr = 0.f, xz = 0.f, xn = 0.f;
        if (t < 256) {
            const f16* xwt = xw + (size_t)ts * XWS;
            xr = (float)xwt[t];
            xz = (float)xwt[t + 256];
            xn = (float)xwt[t + 512];
        }
        // partial dot over chunk q for outputs j0+192i
        const f16x2* hb = &h2[cur][q * 36];
        float a0 = 0.f, a1 = 0.f, a2 = 0.f, a3 = 0.f;
#pragma unroll
        for (int i8 = 0; i8 < 8; ++i8) {
            uint4 u = *(const uint4*)(hb + i8 * 4);
            f16x2 p0 = __builtin_bit_cast(f16x2, u.x);
            f16x2 p1 = __builtin_bit_cast(f16x2, u.y);
            f16x2 p2 = __builtin_bit_cast(f16x2, u.z);
            f16x2 p3 = __builtin_bit_cast(f16x2, u.w);
            int kc = i8 * 4;
            a0 = dot2acc(p0, w[0 * 32 + kc + 0], a0);
            a0 = dot2acc(p1, w[0 * 32 + kc + 1], a0);
            a0 = dot2acc(p2, w[0 * 32 + kc + 2], a0);
            a0 = dot2acc(p3, w[0 * 32 + kc + 3], a0);
            a1 = dot2acc(p0, w[1 * 32 + kc + 0], a1);
            a1 = dot2acc(p1, w[1 * 32 + kc + 1], a1);
            a1 = dot2acc(p2, w[1 * 32 + kc + 2], a1);
            a1 = dot2acc(p3, w[1 * 32 + kc + 3], a1);
            a2 = dot2acc(p0, w[2 * 32 + kc + 0], a2);
            a2 = dot2acc(p1, w[2 * 32 + kc + 1], a2);
            a2 = dot2acc(p2, w[2 * 32 + kc + 2], a2);
            a2 = dot2acc(p3, w[2 * 32 + kc + 3], a2);
            a3 = dot2acc(p0, w[3 * 32 + kc + 0], a3);
            a3 = dot2acc(p1, w[3 * 32 + kc + 1], a3);
            a3 = dot2acc(p2, w[3 * 32 + kc + 2], a3);
            a3 = dot2acc(p3, w[3 * 32 + kc + 3], a3);
        }
        // quad butterfly: full sums for all 4 outputs land in all 4 lanes
        float s0 = a0 + __shfl_xor(a0, 1);
        float s1 = a1 + __shfl_xor(a1, 1);
        float s2 = a2 + __shfl_xor(a2, 1);
        float s3 = a3 + __shfl_xor(a3, 1);
        s0 += __shfl_xor(s0, 2);
        s1 += __shfl_xor(s1, 2);
        s2 += __shfl_xor(s2, 2);
        s3 += __shfl_xor(s3, 2);
        float val = (q == 0) ? s0 : (q == 1) ? s1 : (q == 2) ? s2 : s3;
        hw[mout] = val + bregq;
        __syncthreads();  // hW ready

        if (t < 256) {
            float hr = hw[t], hz = hw[t + 256], hn = hw[t + 512];
            float r = sigmoid_f(xr + hr);
            float z = sigmoid_f(xz + hz);
            float n = tanh_f(xn + r * hn);
            float hnew = (1.f - z) * n + z * hprev;
            hprev = hnew;
            float hpair = __shfl_xor(hnew, 1);
            if (!(t & 1)) {
                f16x2 p;
                p.x = (f16)hnew;
                p.y = (f16)hpair;
                int idx = t >> 1;                      // 0..127
                h2[cur ^ 1][(idx >> 5) * 36 + (idx & 31)] = p;
            }
            if (g) {
                xb16[((size_t)(b * 512 + ts)) * 256 + t] = (f16)hnew;
            } else {
                float p = hnew * waj;
#pragma unroll
                for (int off = 32; off; off >>= 1) p += __shfl_down(p, off);
                if ((t & 63) == 0) spart[t >> 6] = p;
            }
        }
        __syncthreads();  // h(t+1) + spart ready
        if (!g && t == 0)
            scores[b * 512 + ts] = (spart[0] + spart[1]) + (spart[2] + spart[3]);
        cur ^= 1;
    }
}

// ---------------------------------------------------------------- attention
// Prefix softmax == running scan: out[b,t,h] = cumsum(w_s * v[s,h]) / cumsum(w_s),
// w_s = exp(scores[b,s] - max_s scores). One block per batch element. v is f16.
__global__ __launch_bounds__(256) void attn_kernel(
    const float* __restrict__ scores, const f16* __restrict__ v16, float* __restrict__ out)
{
    int b = blockIdx.x, h = threadIdx.x;
    __shared__ float scs[512];
    __shared__ float wle[512];
    __shared__ float red[4];

    scs[h] = scores[b * 512 + h];
    scs[h + 256] = scores[b * 512 + 256 + h];
    __syncthreads();
    float m = fmaxf(scs[h], scs[h + 256]);
#pragma unroll
    for (int off = 32; off; off >>= 1) m = fmaxf(m, __shfl_down(m, off));
    if ((h & 63) == 0) red[h >> 6] = m;
    __syncthreads();
    m = fmaxf(fmaxf(red[0], red[1]), fmaxf(red[2], red[3]));
    wle[h] = __expf(scs[h] - m);
    wle[h + 256] = __expf(scs[h + 256] - m);
    __syncthreads();

    float acc = 0.f, Wc = 0.f;
    const f16* vb = v16 + (size_t)b * 512 * 256 + h;
    float* ob = out + (size_t)b * 512 * 256 + h;
    for (int t8 = 0; t8 < 64; ++t8) {
        float vv[8];
#pragma unroll
        for (int u = 0; u < 8; ++u) vv[u] = (float)vb[(size_t)(t8 * 8 + u) * 256];
#pragma unroll
        for (int u = 0; u < 8; ++u) {
            float wv = wle[t8 * 8 + u];
            Wc += wv;
            acc += wv * vv[u];
            ob[(size_t)(t8 * 8 + u) * 256] = acc * __builtin_amdgcn_rcpf(Wc);
        }
    }
}

// ---------------------------------------------------------------- launch
extern "C" void kernel_launch(void* const* d_in, const int* in_sizes, int n_in,
                              void* d_out, int out_size, void* d_ws, size_t ws_size,
                              hipStream_t stream) {
    const float* x     = (const float*)d_in[0];
    const float* Wp    = (const float*)d_in[1];
    const float* bp    = (const float*)d_in[2];
    const float* Wih_a = (const float*)d_in[3];
    const float* Whh_a = (const float*)d_in[4];
    const float* bih_a = (const float*)d_in[5];
    const float* bhh_a = (const float*)d_in[6];
    const float* Wih_b = (const float*)d_in[7];
    const float* Whh_b = (const float*)d_in[8];
    const float* bih_b = (const float*)d_in[9];
    const float* bhh_b = (const float*)d_in[10];
    const float* Wa    = (const float*)d_in[11];
    // d_in[12] = ba: dropped — softmax is shift-invariant.
    const float* Wb    = (const float*)d_in[13];
    const float* bb    = (const float*)d_in[14];
    float* out = (float*)d_out;

    // Workspace layout (~226 MiB):
    char* ws = (char*)d_ws;
    size_t off = 0;
    auto take = [&](size_t bytes) -> void* {
        void* p = ws + off;
        off += (bytes + 255) & ~(size_t)255;
        return p;
    };
    f16* xp16     = (f16*)take(16777216ull * 2);      // xp [65536,256] f16      32 MiB
    char* xw_reg  = (char*)take(100663296ull * 2);    // xW cat [65536,1536] f16 192 MiB
    f16* xw_cat16 = (f16*)xw_reg;
    f16* v16      = (f16*)xw_reg;                     // alias (xW dead after rnn)
    float* scores = (float*)take(65536ull * 4);
    f16* wp16     = (f16*)take(32768ull * 2);
    f16* wih_cat  = (f16*)take(393216ull * 2);        // rows 0..767 = a, 768..1535 = b
    f16* whha16   = (f16*)take(196608ull * 2);
    f16* whhb16   = (f16*)take(196608ull * 2);
    f16* wb16     = (f16*)take(65536ull * 2);
    // xb (GRU-b hidden states, f16, 32 MiB) lives in d_out; overwritten by attn at the end.
    f16* xb16 = (f16*)d_out;
    (void)ws_size; (void)n_in; (void)in_sizes; (void)out_size;

    // 1. all weight conversions in one kernel (Wih_a/b land adjacent in wih_cat)
    hipLaunchKernelGGL(cvt_weights_kernel, dim3(865), dim3(256), 0, stream,
                       Wp, Wih_a, Whh_a, Wih_b, Whh_b, Wb,
                       wp16, wih_cat, whha16, wih_cat + 768 * 256, whhb16, wb16);
    // 2. xp = x @ Wp^T + bp   (A converted fp32->f16 in staging)
    hipLaunchKernelGGL((gemm_kernel<128, 256, 0, true, (1 << 30)>), dim3(512, 2), dim3(256), 0, stream,
                       (const void*)x, wp16, bp, bp, xp16, (const f16*)nullptr);
    // 3. xW_cat = xp @ [Wih_a;Wih_b]^T + [bih_a;bih_b]
    hipLaunchKernelGGL((gemm_kernel<256, 1536, 1, false, 768>), dim3(512, 12), dim3(256), 0, stream,
                       (const void*)xp16, wih_cat, bih_a, bih_b, xw_cat16, (const f16*)nullptr);
    // 4. both GRUs; fuses scores (GRU a); emits xb f16 into d_out (GRU b)
    hipLaunchKernelGGL(rnn_kernel, dim3(256), dim3(768), 0, stream,
                       xw_cat16, whha16, whhb16, bhh_a, bhh_b, Wa, xb16, scores);
    // 5. beta = tanh(xb @ Wb^T + bb); v = xp * beta  (f16, overwrites xW region)
    hipLaunchKernelGGL((gemm_kernel<256, 256, 2, false, (1 << 30)>), dim3(512, 2), dim3(256), 0, stream,
                       (const void*)xb16, wb16, bb, bb, v16, xp16);
    // 6. causal prefix-softmax attention as a running scan (overwrites xb in d_out)
    hipLaunchKernelGGL(attn_kernel, dim3(128), dim3(256), 0, stream, scores, v16, out);
}

// Round 5
// 1077.853 us; speedup vs baseline: 1.0901x; 1.0901x over previous
//
#include <hip/hip_runtime.h>
#include <hip/hip_bf16.h>

typedef _Float16 f16;
typedef f16 f16x2 __attribute__((ext_vector_type(2)));
typedef f16 f16x8 __attribute__((ext_vector_type(8)));
typedef float f32x4 __attribute__((ext_vector_type(4)));

__device__ __forceinline__ float dot2acc(f16x2 a, f16x2 b, float c) {
    return __builtin_amdgcn_fdot2(a, b, c, false);
}
__device__ __forceinline__ float sigmoid_f(float x) {
    return __builtin_amdgcn_rcpf(1.f + __expf(-x));
}
__device__ __forceinline__ float tanh_f(float x) {
    return 1.f - 2.f * __builtin_amdgcn_rcpf(__expf(2.f * x) + 1.f);
}
// quad-lane DPP shuffle (pure VALU; keeps the LDS pipe free)
template <int CTRL>
__device__ __forceinline__ float dppx(float x) {
    return __builtin_bit_cast(float,
        __builtin_amdgcn_mov_dpp(__builtin_bit_cast(int, x), CTRL, 0xF, 0xF, true));
}
#define DPP_XOR1 0xB1  // quad_perm [1,0,3,2]
#define DPP_XOR2 0x4E  // quad_perm [2,3,0,1]

// ------------------------------------------------- fused weight f32->f16 convert
__global__ __launch_bounds__(256) void cvt_weights_kernel(
    const float* __restrict__ wp, const float* __restrict__ wia, const float* __restrict__ wha,
    const float* __restrict__ wib, const float* __restrict__ whb, const float* __restrict__ wb,
    f16* __restrict__ o_wp, f16* __restrict__ o_wia, f16* __restrict__ o_wha,
    f16* __restrict__ o_wib, f16* __restrict__ o_whb, f16* __restrict__ o_wb)
{
    int i = blockIdx.x * 256 + threadIdx.x;
    if (i >= 221248) return;
    const float* s; f16* d; int off;
    if      (i < 8192)   { s = wp;  d = o_wp;  off = i; }
    else if (i < 57344)  { s = wia; d = o_wia; off = i - 8192; }
    else if (i < 106496) { s = wha; d = o_wha; off = i - 57344; }
    else if (i < 155648) { s = wib; d = o_wib; off = i - 106496; }
    else if (i < 204800) { s = whb; d = o_whb; off = i - 155648; }
    else                 { s = wb;  d = o_wb;  off = i - 204800; }
    float4 f = ((const float4*)s)[off];
    f16x2 p0; p0.x = (f16)f.x; p0.y = (f16)f.y;
    f16x2 p1; p1.x = (f16)f.z; p1.y = (f16)f.w;
    ((f16x2*)d)[off * 2]     = p0;
    ((f16x2*)d)[off * 2 + 1] = p1;
}

// ---------------------------------------------------------------- MFMA GEMM
#define BM 128
#define BN 128
#define BKC 64
#define LPAD 8

template <int KT, int NOUT, int EPI, bool CVTA, int BSPLIT>
__global__ __launch_bounds__(256) void gemm_kernel(
    const void* __restrict__ Araw, const f16* __restrict__ B,
    const float* __restrict__ bias, const float* __restrict__ bias2,
    f16* __restrict__ out16, const f16* __restrict__ xp16)
{
    __shared__ __align__(16) f16 As[BM][BKC + LPAD];
    __shared__ __align__(16) f16 Bs[BN][BKC + LPAD];
    int tid = threadIdx.x;
    int m0 = blockIdx.x * BM, n0 = blockIdx.y * BN;
    int wave = tid >> 6, lane = tid & 63;
    int wm = (wave & 1) * 64, wn = (wave >> 1) * 64;
    int quad = lane >> 4, l16 = lane & 15;

    f32x4 acc[4][4] = {};

    for (int kc = 0; kc < KT / BKC; ++kc) {
        __syncthreads();
#pragma unroll
        for (int i = 0; i < 4; ++i) {
            int idx = i * 256 + tid;
            int row = idx >> 3, c8 = idx & 7;
            if (CVTA) {
                const float* A32 = (const float*)Araw;
                const float* src = A32 + (size_t)(m0 + row) * KT + kc * BKC + c8 * 8;
                float4 fa = *(const float4*)src;
                float4 fb = *(const float4*)(src + 4);
                f16x8 h8;
                h8[0] = (f16)fa.x; h8[1] = (f16)fa.y; h8[2] = (f16)fa.z; h8[3] = (f16)fa.w;
                h8[4] = (f16)fb.x; h8[5] = (f16)fb.y; h8[6] = (f16)fb.z; h8[7] = (f16)fb.w;
                *(f16x8*)&As[row][c8 * 8] = h8;
            } else {
                const f16* A16 = (const f16*)Araw;
                uint4 va = *(const uint4*)(A16 + (size_t)(m0 + row) * KT + kc * BKC + c8 * 8);
                *(uint4*)&As[row][c8 * 8] = va;
            }
            uint4 vb = *(const uint4*)(B + (size_t)(n0 + row) * KT + kc * BKC + c8 * 8);
            *(uint4*)&Bs[row][c8 * 8] = vb;
        }
        __syncthreads();
#pragma unroll
        for (int kk = 0; kk < 2; ++kk) {
            f16x8 af[4], bf[4];
#pragma unroll
            for (int i = 0; i < 4; ++i) {
                af[i] = *(const f16x8*)&As[wm + i * 16 + l16][kk * 32 + quad * 8];
                bf[i] = *(const f16x8*)&Bs[wn + i * 16 + l16][kk * 32 + quad * 8];
            }
#pragma unroll
            for (int mi = 0; mi < 4; ++mi)
#pragma unroll
                for (int ni = 0; ni < 4; ++ni)
                    acc[mi][ni] = __builtin_amdgcn_mfma_f32_16x16x32_f16(af[mi], bf[ni], acc[mi][ni], 0, 0, 0);
        }
    }

#pragma unroll
    for (int ni = 0; ni < 4; ++ni) {
        int col = n0 + wn + ni * 16 + l16;
        float bv = (col < BSPLIT) ? bias[col] : bias2[col - BSPLIT];
#pragma unroll
        for (int mi = 0; mi < 4; ++mi) {
#pragma unroll
            for (int r = 0; r < 4; ++r) {
                int row = m0 + wm + mi * 16 + quad * 4 + r;
                float val = acc[mi][ni][r] + bv;
                if (EPI == 2) {
                    float tb = tanh_f(val);
                    float xpv = (float)xp16[(size_t)row * NOUT + col];
                    out16[(size_t)row * NOUT + col] = (f16)(tb * xpv);
                } else {
                    out16[(size_t)row * NOUT + col] = (f16)val;
                }
            }
        }
    }
}

// ---------------------------------------------------------------- GRU recurrence
// 256 blocks: blockIdx>>7 = GRU (0=a,1=b), &127 = batch element. 768 threads.
// Thread t = (j0 = t>>2, q = t&3): holds Whh rows {j0+192i} over h-chunk q as
// 128 scalar uints (f16x2 pairs), each PINNED via a scalar asm register-tie so
// the compiler cannot rematerialize the loads inside the loop (round-2/3 bug:
// VGPR_Count=84 -> weights re-fetched from L2 every step, ~900 us).
// Dot: 8 ds_read_b128 of chunk q (144-B chunk stride -> disjoint banks, broadcast).
// Quad reduce: DPP quad_perm (VALU), lane q writes output j0+192q into padded hw.
#define XWS 1536

__global__ __launch_bounds__(768, 3) void rnn_kernel(
    const f16* __restrict__ xw_cat,
    const f16* __restrict__ whha, const f16* __restrict__ whhb,
    const float* __restrict__ bhha, const float* __restrict__ bhhb,
    const float* __restrict__ Wa,
    f16* __restrict__ xb16, float* __restrict__ scores)
{
    int g = blockIdx.x >> 7, b = blockIdx.x & 127;
    int t = threadIdx.x;
    int q = t & 3, j0 = t >> 2;          // k-chunk, output group

    const f16* whh = g ? whhb : whha;
    const float* bhh = g ? bhhb : bhha;
    const f16* xw = xw_cat + (size_t)b * 512 * XWS + 768 * g;

    // weights: 4 outputs x (64 h-elems of chunk q) = 128 f16x2 = 128 VGPRs
    unsigned int w[128];
#pragma unroll
    for (int i = 0; i < 4; ++i) {
        const f16* src = whh + (size_t)(j0 + 192 * i) * 256 + q * 64;
#pragma unroll
        for (int b8 = 0; b8 < 8; ++b8) {
            uint4 u = *(const uint4*)(src + b8 * 8);
            w[i * 32 + b8 * 4 + 0] = u.x;
            w[i * 32 + b8 * 4 + 1] = u.y;
            w[i * 32 + b8 * 4 + 2] = u.z;
            w[i * 32 + b8 * 4 + 3] = u.w;
        }
    }
#pragma unroll
    for (int i = 0; i < 128; ++i) asm volatile("" : "+v"(w[i]));  // pin in VGPRs

    float bregq = bhh[j0 + 192 * q];
    float waj = (t < 256) ? Wa[t] : 0.f;

    // h chunks padded: chunk c at f16x2 offset c*36 (144-B stride -> disjoint banks)
    __shared__ __align__(16) f16x2 h2[2][144];
    __shared__ float hw[800];            // logical m=j0+192i stored at j0+200i
    __shared__ float spart[4];

    // consumer-side physical indices (phys = m + 8*(m/192)), computed once
    int p1 = t + 8 * (t / 192);
    int p2 = (t + 256) + 8 * ((t + 256) / 192);
    int p3 = (t + 512) + 8 * ((t + 512) / 192);

    if (t < 144) { h2[0][t] = __builtin_bit_cast(f16x2, 0u); }
    __syncthreads();

    float hprev = 0.f;
    int cur = 0;
    for (int ts = 0; ts < 512; ++ts) {
        float xr = 0.f, xz = 0.f, xn = 0.f;
        if (t < 256) {
            const f16* xwt = xw + (size_t)ts * XWS;
            xr = (float)xwt[t];
            xz = (float)xwt[t + 256];
            xn = (float)xwt[t + 512];
        }
        // partial dot over chunk q for outputs j0+192i
        const f16x2* hb = &h2[cur][q * 36];
        float a0 = 0.f, a1 = 0.f, a2 = 0.f, a3 = 0.f;
#pragma unroll
        for (int i8 = 0; i8 < 8; ++i8) {
            uint4 u = *(const uint4*)(hb + i8 * 4);
            f16x2 p0 = __builtin_bit_cast(f16x2, u.x);
            f16x2 p1h = __builtin_bit_cast(f16x2, u.y);
            f16x2 p2h = __builtin_bit_cast(f16x2, u.z);
            f16x2 p3h = __builtin_bit_cast(f16x2, u.w);
            int kc = i8 * 4;
            a0 = dot2acc(p0,  __builtin_bit_cast(f16x2, w[0 * 32 + kc + 0]), a0);
            a0 = dot2acc(p1h, __builtin_bit_cast(f16x2, w[0 * 32 + kc + 1]), a0);
            a0 = dot2acc(p2h, __builtin_bit_cast(f16x2, w[0 * 32 + kc + 2]), a0);
            a0 = dot2acc(p3h, __builtin_bit_cast(f16x2, w[0 * 32 + kc + 3]), a0);
            a1 = dot2acc(p0,  __builtin_bit_cast(f16x2, w[1 * 32 + kc + 0]), a1);
            a1 = dot2acc(p1h, __builtin_bit_cast(f16x2, w[1 * 32 + kc + 1]), a1);
            a1 = dot2acc(p2h, __builtin_bit_cast(f16x2, w[1 * 32 + kc + 2]), a1);
            a1 = dot2acc(p3h, __builtin_bit_cast(f16x2, w[1 * 32 + kc + 3]), a1);
            a2 = dot2acc(p0,  __builtin_bit_cast(f16x2, w[2 * 32 + kc + 0]), a2);
            a2 = dot2acc(p1h, __builtin_bit_cast(f16x2, w[2 * 32 + kc + 1]), a2);
            a2 = dot2acc(p2h, __builtin_bit_cast(f16x2, w[2 * 32 + kc + 2]), a2);
            a2 = dot2acc(p3h, __builtin_bit_cast(f16x2, w[2 * 32 + kc + 3]), a2);
            a3 = dot2acc(p0,  __builtin_bit_cast(f16x2, w[3 * 32 + kc + 0]), a3);
            a3 = dot2acc(p1h, __builtin_bit_cast(f16x2, w[3 * 32 + kc + 1]), a3);
            a3 = dot2acc(p2h, __builtin_bit_cast(f16x2, w[3 * 32 + kc + 2]), a3);
            a3 = dot2acc(p3h, __builtin_bit_cast(f16x2, w[3 * 32 + kc + 3]), a3);
        }
        // quad butterfly via DPP (VALU pipe)
        float s0 = a0 + dppx<DPP_XOR1>(a0);
        float s1 = a1 + dppx<DPP_XOR1>(a1);
        float s2 = a2 + dppx<DPP_XOR1>(a2);
        float s3 = a3 + dppx<DPP_XOR1>(a3);
        s0 += dppx<DPP_XOR2>(s0);
        s1 += dppx<DPP_XOR2>(s1);
        s2 += dppx<DPP_XOR2>(s2);
        s3 += dppx<DPP_XOR2>(s3);
        float val = (q == 0) ? s0 : (q == 1) ? s1 : (q == 2) ? s2 : s3;
        hw[j0 + 200 * q] = val + bregq;   // padded: worst 2-way bank alias (free)
        __syncthreads();  // hW ready

        if (t < 256) {
            float hr = hw[p1], hz = hw[p2], hn = hw[p3];
            float r = sigmoid_f(xr + hr);
            float z = sigmoid_f(xz + hz);
            float n = tanh_f(xn + r * hn);
            float hnew = (1.f - z) * n + z * hprev;
            hprev = hnew;
            float hpair = dppx<DPP_XOR1>(hnew);
            if (!(t & 1)) {
                f16x2 p;
                p.x = (f16)hnew;
                p.y = (f16)hpair;
                int idx = t >> 1;                      // 0..127
                h2[cur ^ 1][(idx >> 5) * 36 + (idx & 31)] = p;
            }
            if (g) {
                xb16[((size_t)(b * 512 + ts)) * 256 + t] = (f16)hnew;
            } else {
                float p = hnew * waj;
#pragma unroll
                for (int off = 32; off; off >>= 1) p += __shfl_down(p, off);
                if ((t & 63) == 0) spart[t >> 6] = p;
            }
        }
        __syncthreads();  // h(t+1) + spart ready
        if (!g && t == 0)
            scores[b * 512 + ts] = (spart[0] + spart[1]) + (spart[2] + spart[3]);
        cur ^= 1;
    }
}

// ---------------------------------------------------------------- attention
// Running-scan prefix softmax. Grid (128 batches, 2 h-halves) x 128 threads.
__global__ __launch_bounds__(128) void attn_kernel(
    const float* __restrict__ scores, const f16* __restrict__ v16, float* __restrict__ out)
{
    int b = blockIdx.x, tx = threadIdx.x;
    int h = blockIdx.y * 128 + tx;
    __shared__ float wle[512];
    __shared__ float red[2];

    float s0 = scores[b * 512 + tx];
    float s1 = scores[b * 512 + 128 + tx];
    float s2 = scores[b * 512 + 256 + tx];
    float s3 = scores[b * 512 + 384 + tx];
    float m = fmaxf(fmaxf(s0, s1), fmaxf(s2, s3));
#pragma unroll
    for (int off = 32; off; off >>= 1) m = fmaxf(m, __shfl_down(m, off));
    if ((tx & 63) == 0) red[tx >> 6] = m;
    __syncthreads();
    m = fmaxf(red[0], red[1]);
    wle[tx]       = __expf(s0 - m);
    wle[tx + 128] = __expf(s1 - m);
    wle[tx + 256] = __expf(s2 - m);
    wle[tx + 384] = __expf(s3 - m);
    __syncthreads();

    float acc = 0.f, Wc = 0.f;
    const f16* vb = v16 + (size_t)b * 512 * 256 + h;
    float* ob = out + (size_t)b * 512 * 256 + h;
    for (int t8 = 0; t8 < 64; ++t8) {
        float vv[8];
#pragma unroll
        for (int u = 0; u < 8; ++u) vv[u] = (float)vb[(size_t)(t8 * 8 + u) * 256];
#pragma unroll
        for (int u = 0; u < 8; ++u) {
            float wv = wle[t8 * 8 + u];
            Wc += wv;
            acc += wv * vv[u];
            ob[(size_t)(t8 * 8 + u) * 256] = acc * __builtin_amdgcn_rcpf(Wc);
        }
    }
}

// ---------------------------------------------------------------- launch
extern "C" void kernel_launch(void* const* d_in, const int* in_sizes, int n_in,
                              void* d_out, int out_size, void* d_ws, size_t ws_size,
                              hipStream_t stream) {
    const float* x     = (const float*)d_in[0];
    const float* Wp    = (const float*)d_in[1];
    const float* bp    = (const float*)d_in[2];
    const float* Wih_a = (const float*)d_in[3];
    const float* Whh_a = (const float*)d_in[4];
    const float* bih_a = (const float*)d_in[5];
    const float* bhh_a = (const float*)d_in[6];
    const float* Wih_b = (const float*)d_in[7];
    const float* Whh_b = (const float*)d_in[8];
    const float* bih_b = (const float*)d_in[9];
    const float* bhh_b = (const float*)d_in[10];
    const float* Wa    = (const float*)d_in[11];
    // d_in[12] = ba: dropped — softmax is shift-invariant.
    const float* Wb    = (const float*)d_in[13];
    const float* bb    = (const float*)d_in[14];
    float* out = (float*)d_out;

    char* ws = (char*)d_ws;
    size_t off = 0;
    auto take = [&](size_t bytes) -> void* {
        void* p = ws + off;
        off += (bytes + 255) & ~(size_t)255;
        return p;
    };
    f16* xp16     = (f16*)take(16777216ull * 2);      // xp [65536,256] f16      32 MiB
    char* xw_reg  = (char*)take(100663296ull * 2);    // xW cat [65536,1536] f16 192 MiB
    f16* xw_cat16 = (f16*)xw_reg;
    f16* v16      = (f16*)xw_reg;                     // alias (xW dead after rnn)
    float* scores = (float*)take(65536ull * 4);
    f16* wp16     = (f16*)take(32768ull * 2);
    f16* wih_cat  = (f16*)take(393216ull * 2);        // rows 0..767 = a, 768..1535 = b
    f16* whha16   = (f16*)take(196608ull * 2);
    f16* whhb16   = (f16*)take(196608ull * 2);
    f16* wb16     = (f16*)take(65536ull * 2);
    f16* xb16 = (f16*)d_out;  // GRU-b hidden states live in d_out; attn overwrites later
    (void)ws_size; (void)n_in; (void)in_sizes; (void)out_size;

    hipLaunchKernelGGL(cvt_weights_kernel, dim3(865), dim3(256), 0, stream,
                       Wp, Wih_a, Whh_a, Wih_b, Whh_b, Wb,
                       wp16, wih_cat, whha16, wih_cat + 768 * 256, whhb16, wb16);
    hipLaunchKernelGGL((gemm_kernel<128, 256, 0, true, (1 << 30)>), dim3(512, 2), dim3(256), 0, stream,
                       (const void*)x, wp16, bp, bp, xp16, (const f16*)nullptr);
    hipLaunchKernelGGL((gemm_kernel<256, 1536, 1, false, 768>), dim3(512, 12), dim3(256), 0, stream,
                       (const void*)xp16, wih_cat, bih_a, bih_b, xw_cat16, (const f16*)nullptr);
    hipLaunchKernelGGL(rnn_kernel, dim3(256), dim3(768), 0, stream,
                       xw_cat16, whha16, whhb16, bhh_a, bhh_b, Wa, xb16, scores);
    hipLaunchKernelGGL((gemm_kernel<256, 256, 2, false, (1 << 30)>), dim3(512, 2), dim3(256), 0, stream,
                       (const void*)xb16, wb16, bb, bb, v16, xp16);
    hipLaunchKernelGGL(attn_kernel, dim3(128, 2), dim3(128), 0, stream, scores, v16, out);
}

// Round 6
// 1073.890 us; speedup vs baseline: 1.0941x; 1.0037x over previous
//
#include <hip/hip_runtime.h>
#include <hip/hip_bf16.h>

typedef _Float16 f16;
typedef f16 f16x2 __attribute__((ext_vector_type(2)));
typedef f16 f16x8 __attribute__((ext_vector_type(8)));
typedef float f32x4 __attribute__((ext_vector_type(4)));

__device__ __forceinline__ float dot2acc(f16x2 a, f16x2 b, float c) {
    return __builtin_amdgcn_fdot2(a, b, c, false);
}
__device__ __forceinline__ float sigmoid_f(float x) {
    return __builtin_amdgcn_rcpf(1.f + __expf(-x));
}
__device__ __forceinline__ float tanh_f(float x) {
    return 1.f - 2.f * __builtin_amdgcn_rcpf(__expf(2.f * x) + 1.f);
}
// quad-lane DPP shuffle (pure VALU; keeps the LDS pipe free)
template <int CTRL>
__device__ __forceinline__ float dppx(float x) {
    return __builtin_bit_cast(float,
        __builtin_amdgcn_mov_dpp(__builtin_bit_cast(int, x), CTRL, 0xF, 0xF, true));
}
#define DPP_XOR1 0xB1  // quad_perm [1,0,3,2]
#define DPP_XOR2 0x4E  // quad_perm [2,3,0,1]

// ------------------------------------------------- fused weight f32->f16 convert
__global__ __launch_bounds__(256) void cvt_weights_kernel(
    const float* __restrict__ wp, const float* __restrict__ wia, const float* __restrict__ wha,
    const float* __restrict__ wib, const float* __restrict__ whb, const float* __restrict__ wb,
    f16* __restrict__ o_wp, f16* __restrict__ o_wia, f16* __restrict__ o_wha,
    f16* __restrict__ o_wib, f16* __restrict__ o_whb, f16* __restrict__ o_wb)
{
    int i = blockIdx.x * 256 + threadIdx.x;
    if (i >= 221248) return;
    const float* s; f16* d; int off;
    if      (i < 8192)   { s = wp;  d = o_wp;  off = i; }
    else if (i < 57344)  { s = wia; d = o_wia; off = i - 8192; }
    else if (i < 106496) { s = wha; d = o_wha; off = i - 57344; }
    else if (i < 155648) { s = wib; d = o_wib; off = i - 106496; }
    else if (i < 204800) { s = whb; d = o_whb; off = i - 155648; }
    else                 { s = wb;  d = o_wb;  off = i - 204800; }
    float4 f = ((const float4*)s)[off];
    f16x2 p0; p0.x = (f16)f.x; p0.y = (f16)f.y;
    f16x2 p1; p1.x = (f16)f.z; p1.y = (f16)f.w;
    ((f16x2*)d)[off * 2]     = p0;
    ((f16x2*)d)[off * 2 + 1] = p1;
}

// ---------------------------------------------------------------- MFMA GEMM
#define BM 128
#define BN 128
#define BKC 64
#define LPAD 8

template <int KT, int NOUT, int EPI, bool CVTA, int BSPLIT>
__global__ __launch_bounds__(256) void gemm_kernel(
    const void* __restrict__ Araw, const f16* __restrict__ B,
    const float* __restrict__ bias, const float* __restrict__ bias2,
    f16* __restrict__ out16, const f16* __restrict__ xp16)
{
    __shared__ __align__(16) f16 As[BM][BKC + LPAD];
    __shared__ __align__(16) f16 Bs[BN][BKC + LPAD];
    int tid = threadIdx.x;
    int m0 = blockIdx.x * BM, n0 = blockIdx.y * BN;
    int wave = tid >> 6, lane = tid & 63;
    int wm = (wave & 1) * 64, wn = (wave >> 1) * 64;
    int quad = lane >> 4, l16 = lane & 15;

    f32x4 acc[4][4] = {};

    for (int kc = 0; kc < KT / BKC; ++kc) {
        __syncthreads();
#pragma unroll
        for (int i = 0; i < 4; ++i) {
            int idx = i * 256 + tid;
            int row = idx >> 3, c8 = idx & 7;
            if (CVTA) {
                const float* A32 = (const float*)Araw;
                const float* src = A32 + (size_t)(m0 + row) * KT + kc * BKC + c8 * 8;
                float4 fa = *(const float4*)src;
                float4 fb = *(const float4*)(src + 4);
                f16x8 h8;
                h8[0] = (f16)fa.x; h8[1] = (f16)fa.y; h8[2] = (f16)fa.z; h8[3] = (f16)fa.w;
                h8[4] = (f16)fb.x; h8[5] = (f16)fb.y; h8[6] = (f16)fb.z; h8[7] = (f16)fb.w;
                *(f16x8*)&As[row][c8 * 8] = h8;
            } else {
                const f16* A16 = (const f16*)Araw;
                uint4 va = *(const uint4*)(A16 + (size_t)(m0 + row) * KT + kc * BKC + c8 * 8);
                *(uint4*)&As[row][c8 * 8] = va;
            }
            uint4 vb = *(const uint4*)(B + (size_t)(n0 + row) * KT + kc * BKC + c8 * 8);
            *(uint4*)&Bs[row][c8 * 8] = vb;
        }
        __syncthreads();
#pragma unroll
        for (int kk = 0; kk < 2; ++kk) {
            f16x8 af[4], bf[4];
#pragma unroll
            for (int i = 0; i < 4; ++i) {
                af[i] = *(const f16x8*)&As[wm + i * 16 + l16][kk * 32 + quad * 8];
                bf[i] = *(const f16x8*)&Bs[wn + i * 16 + l16][kk * 32 + quad * 8];
            }
#pragma unroll
            for (int mi = 0; mi < 4; ++mi)
#pragma unroll
                for (int ni = 0; ni < 4; ++ni)
                    acc[mi][ni] = __builtin_amdgcn_mfma_f32_16x16x32_f16(af[mi], bf[ni], acc[mi][ni], 0, 0, 0);
        }
    }

#pragma unroll
    for (int ni = 0; ni < 4; ++ni) {
        int col = n0 + wn + ni * 16 + l16;
        float bv = (col < BSPLIT) ? bias[col] : bias2[col - BSPLIT];
#pragma unroll
        for (int mi = 0; mi < 4; ++mi) {
#pragma unroll
            for (int r = 0; r < 4; ++r) {
                int row = m0 + wm + mi * 16 + quad * 4 + r;
                float val = acc[mi][ni][r] + bv;
                if (EPI == 2) {
                    float tb = tanh_f(val);
                    float xpv = (float)xp16[(size_t)row * NOUT + col];
                    out16[(size_t)row * NOUT + col] = (f16)(tb * xpv);
                } else {
                    out16[(size_t)row * NOUT + col] = (f16)val;
                }
            }
        }
    }
}

// ---------------------------------------------------------------- GRU recurrence
// 256 blocks (1/CU): blockIdx>>7 = GRU (0=a,1=b), &127 = batch element. 768 threads.
// Thread t = (j0 = t>>2, q = t&3): holds Whh rows {j0+192i} over h-chunk q as
// 128 scalar uints (f16x2), pinned via scalar asm ties.
// amdgpu_waves_per_eu(3,3): grid = 1 block/CU = 12 waves = 3 waves/EU, so demand
// EXACTLY 3 waves/EU -> 170-VGPR budget -> w[] stays in arch VGPRs (round-5 bug:
// allocator targeted 6 waves/EU, parked w[] in AGPRs, +1 v_accvgpr_read per dot2).
// Dot: 8 ds_read_b128 of chunk q (144-B chunk stride -> disjoint banks, broadcast).
// Quad reduce: DPP quad_perm (VALU), lane q writes output j0+192q into padded hw.
#define XWS 1536

__global__ __launch_bounds__(768)
__attribute__((amdgpu_waves_per_eu(3, 3)))
void rnn_kernel(
    const f16* __restrict__ xw_cat,
    const f16* __restrict__ whha, const f16* __restrict__ whhb,
    const float* __restrict__ bhha, const float* __restrict__ bhhb,
    const float* __restrict__ Wa,
    f16* __restrict__ xb16, float* __restrict__ scores)
{
    int g = blockIdx.x >> 7, b = blockIdx.x & 127;
    int t = threadIdx.x;
    int q = t & 3, j0 = t >> 2;          // k-chunk, output group

    const f16* whh = g ? whhb : whha;
    const float* bhh = g ? bhhb : bhha;
    const f16* xw = xw_cat + (size_t)b * 512 * XWS + 768 * g;

    // weights: 4 outputs x (64 h-elems of chunk q) = 128 f16x2 = 128 VGPRs
    unsigned int w[128];
#pragma unroll
    for (int i = 0; i < 4; ++i) {
        const f16* src = whh + (size_t)(j0 + 192 * i) * 256 + q * 64;
#pragma unroll
        for (int b8 = 0; b8 < 8; ++b8) {
            uint4 u = *(const uint4*)(src + b8 * 8);
            w[i * 32 + b8 * 4 + 0] = u.x;
            w[i * 32 + b8 * 4 + 1] = u.y;
            w[i * 32 + b8 * 4 + 2] = u.z;
            w[i * 32 + b8 * 4 + 3] = u.w;
        }
    }
#pragma unroll
    for (int i = 0; i < 128; ++i) asm volatile("" : "+v"(w[i]));  // pin in VGPRs

    float bregq = bhh[j0 + 192 * q];
    float waj = (t < 256) ? Wa[t] : 0.f;

    // h chunks padded: chunk c at f16x2 offset c*36 (144-B stride -> disjoint banks)
    __shared__ __align__(16) f16x2 h2[2][144];
    __shared__ float hw[800];            // logical m=j0+192i stored at j0+200i
    __shared__ float spart[4];

    // consumer-side physical indices (phys = m + 8*(m/192)), computed once
    int p1 = t + 8 * (t / 192);
    int p2 = (t + 256) + 8 * ((t + 256) / 192);
    int p3 = (t + 512) + 8 * ((t + 512) / 192);

    if (t < 144) { h2[0][t] = __builtin_bit_cast(f16x2, 0u); }
    __syncthreads();

    float hprev = 0.f;
    int cur = 0;
    for (int ts = 0; ts < 512; ++ts) {
        float xr = 0.f, xz = 0.f, xn = 0.f;
        if (t < 256) {
            const f16* xwt = xw + (size_t)ts * XWS;
            xr = (float)xwt[t];
            xz = (float)xwt[t + 256];
            xn = (float)xwt[t + 512];
        }
        // partial dot over chunk q for outputs j0+192i
        const f16x2* hb = &h2[cur][q * 36];
        float a0 = 0.f, a1 = 0.f, a2 = 0.f, a3 = 0.f;
#pragma unroll
        for (int i8 = 0; i8 < 8; ++i8) {
            uint4 u = *(const uint4*)(hb + i8 * 4);
            f16x2 p0 = __builtin_bit_cast(f16x2, u.x);
            f16x2 p1h = __builtin_bit_cast(f16x2, u.y);
            f16x2 p2h = __builtin_bit_cast(f16x2, u.z);
            f16x2 p3h = __builtin_bit_cast(f16x2, u.w);
            int kc = i8 * 4;
            a0 = dot2acc(p0,  __builtin_bit_cast(f16x2, w[0 * 32 + kc + 0]), a0);
            a0 = dot2acc(p1h, __builtin_bit_cast(f16x2, w[0 * 32 + kc + 1]), a0);
            a0 = dot2acc(p2h, __builtin_bit_cast(f16x2, w[0 * 32 + kc + 2]), a0);
            a0 = dot2acc(p3h, __builtin_bit_cast(f16x2, w[0 * 32 + kc + 3]), a0);
            a1 = dot2acc(p0,  __builtin_bit_cast(f16x2, w[1 * 32 + kc + 0]), a1);
            a1 = dot2acc(p1h, __builtin_bit_cast(f16x2, w[1 * 32 + kc + 1]), a1);
            a1 = dot2acc(p2h, __builtin_bit_cast(f16x2, w[1 * 32 + kc + 2]), a1);
            a1 = dot2acc(p3h, __builtin_bit_cast(f16x2, w[1 * 32 + kc + 3]), a1);
            a2 = dot2acc(p0,  __builtin_bit_cast(f16x2, w[2 * 32 + kc + 0]), a2);
            a2 = dot2acc(p1h, __builtin_bit_cast(f16x2, w[2 * 32 + kc + 1]), a2);
            a2 = dot2acc(p2h, __builtin_bit_cast(f16x2, w[2 * 32 + kc + 2]), a2);
            a2 = dot2acc(p3h, __builtin_bit_cast(f16x2, w[2 * 32 + kc + 3]), a2);
            a3 = dot2acc(p0,  __builtin_bit_cast(f16x2, w[3 * 32 + kc + 0]), a3);
            a3 = dot2acc(p1h, __builtin_bit_cast(f16x2, w[3 * 32 + kc + 1]), a3);
            a3 = dot2acc(p2h, __builtin_bit_cast(f16x2, w[3 * 32 + kc + 2]), a3);
            a3 = dot2acc(p3h, __builtin_bit_cast(f16x2, w[3 * 32 + kc + 3]), a3);
        }
        // quad butterfly via DPP (VALU pipe)
        float s0 = a0 + dppx<DPP_XOR1>(a0);
        float s1 = a1 + dppx<DPP_XOR1>(a1);
        float s2 = a2 + dppx<DPP_XOR1>(a2);
        float s3 = a3 + dppx<DPP_XOR1>(a3);
        s0 += dppx<DPP_XOR2>(s0);
        s1 += dppx<DPP_XOR2>(s1);
        s2 += dppx<DPP_XOR2>(s2);
        s3 += dppx<DPP_XOR2>(s3);
        float val = (q == 0) ? s0 : (q == 1) ? s1 : (q == 2) ? s2 : s3;
        hw[j0 + 200 * q] = val + bregq;   // padded: worst 2-way bank alias (free)
        __syncthreads();  // hW ready

        if (t < 256) {
            float hr = hw[p1], hz = hw[p2], hn = hw[p3];
            float r = sigmoid_f(xr + hr);
            float z = sigmoid_f(xz + hz);
            float n = tanh_f(xn + r * hn);
            float hnew = (1.f - z) * n + z * hprev;
            hprev = hnew;
            float hpair = dppx<DPP_XOR1>(hnew);
            if (!(t & 1)) {
                f16x2 p;
                p.x = (f16)hnew;
                p.y = (f16)hpair;
                int idx = t >> 1;                      // 0..127
                h2[cur ^ 1][(idx >> 5) * 36 + (idx & 31)] = p;
            }
            if (g) {
                xb16[((size_t)(b * 512 + ts)) * 256 + t] = (f16)hnew;
            } else {
                float p = hnew * waj;
#pragma unroll
                for (int off = 32; off; off >>= 1) p += __shfl_down(p, off);
                if ((t & 63) == 0) spart[t >> 6] = p;
            }
        }
        __syncthreads();  // h(t+1) + spart ready
        if (!g && t == 0)
            scores[b * 512 + ts] = (spart[0] + spart[1]) + (spart[2] + spart[3]);
        cur ^= 1;
    }
}

// ---------------------------------------------------------------- attention
// Running-scan prefix softmax. Grid (128 batches, 2 h-halves) x 128 threads.
__global__ __launch_bounds__(128) void attn_kernel(
    const float* __restrict__ scores, const f16* __restrict__ v16, float* __restrict__ out)
{
    int b = blockIdx.x, tx = threadIdx.x;
    int h = blockIdx.y * 128 + tx;
    __shared__ float wle[512];
    __shared__ float red[2];

    float s0 = scores[b * 512 + tx];
    float s1 = scores[b * 512 + 128 + tx];
    float s2 = scores[b * 512 + 256 + tx];
    float s3 = scores[b * 512 + 384 + tx];
    float m = fmaxf(fmaxf(s0, s1), fmaxf(s2, s3));
#pragma unroll
    for (int off = 32; off; off >>= 1) m = fmaxf(m, __shfl_down(m, off));
    if ((tx & 63) == 0) red[tx >> 6] = m;
    __syncthreads();
    m = fmaxf(red[0], red[1]);
    wle[tx]       = __expf(s0 - m);
    wle[tx + 128] = __expf(s1 - m);
    wle[tx + 256] = __expf(s2 - m);
    wle[tx + 384] = __expf(s3 - m);
    __syncthreads();

    float acc = 0.f, Wc = 0.f;
    const f16* vb = v16 + (size_t)b * 512 * 256 + h;
    float* ob = out + (size_t)b * 512 * 256 + h;
    for (int t8 = 0; t8 < 64; ++t8) {
        float vv[8];
#pragma unroll
        for (int u = 0; u < 8; ++u) vv[u] = (float)vb[(size_t)(t8 * 8 + u) * 256];
#pragma unroll
        for (int u = 0; u < 8; ++u) {
            float wv = wle[t8 * 8 + u];
            Wc += wv;
            acc += wv * vv[u];
            ob[(size_t)(t8 * 8 + u) * 256] = acc * __builtin_amdgcn_rcpf(Wc);
        }
    }
}

// ---------------------------------------------------------------- launch
extern "C" void kernel_launch(void* const* d_in, const int* in_sizes, int n_in,
                              void* d_out, int out_size, void* d_ws, size_t ws_size,
                              hipStream_t stream) {
    const float* x     = (const float*)d_in[0];
    const float* Wp    = (const float*)d_in[1];
    const float* bp    = (const float*)d_in[2];
    const float* Wih_a = (const float*)d_in[3];
    const float* Whh_a = (const float*)d_in[4];
    const float* bih_a = (const float*)d_in[5];
    const float* bhh_a = (const float*)d_in[6];
    const float* Wih_b = (const float*)d_in[7];
    const float* Whh_b = (const float*)d_in[8];
    const float* bih_b = (const float*)d_in[9];
    const float* bhh_b = (const float*)d_in[10];
    const float* Wa    = (const float*)d_in[11];
    // d_in[12] = ba: dropped — softmax is shift-invariant.
    const float* Wb    = (const float*)d_in[13];
    const float* bb    = (const float*)d_in[14];
    float* out = (float*)d_out;

    char* ws = (char*)d_ws;
    size_t off = 0;
    auto take = [&](size_t bytes) -> void* {
        void* p = ws + off;
        off += (bytes + 255) & ~(size_t)255;
        return p;
    };
    f16* xp16     = (f16*)take(16777216ull * 2);      // xp [65536,256] f16      32 MiB
    char* xw_reg  = (char*)take(100663296ull * 2);    // xW cat [65536,1536] f16 192 MiB
    f16* xw_cat16 = (f16*)xw_reg;
    f16* v16      = (f16*)xw_reg;                     // alias (xW dead after rnn)
    float* scores = (float*)take(65536ull * 4);
    f16* wp16     = (f16*)take(32768ull * 2);
    f16* wih_cat  = (f16*)take(393216ull * 2);        // rows 0..767 = a, 768..1535 = b
    f16* whha16   = (f16*)take(196608ull * 2);
    f16* whhb16   = (f16*)take(196608ull * 2);
    f16* wb16     = (f16*)take(65536ull * 2);
    f16* xb16 = (f16*)d_out;  // GRU-b hidden states live in d_out; attn overwrites later
    (void)ws_size; (void)n_in; (void)in_sizes; (void)out_size;

    hipLaunchKernelGGL(cvt_weights_kernel, dim3(865), dim3(256), 0, stream,
                       Wp, Wih_a, Whh_a, Wih_b, Whh_b, Wb,
                       wp16, wih_cat, whha16, wih_cat + 768 * 256, whhb16, wb16);
    hipLaunchKernelGGL((gemm_kernel<128, 256, 0, true, (1 << 30)>), dim3(512, 2), dim3(256), 0, stream,
                       (const void*)x, wp16, bp, bp, xp16, (const f16*)nullptr);
    hipLaunchKernelGGL((gemm_kernel<256, 1536, 1, false, 768>), dim3(512, 12), dim3(256), 0, stream,
                       (const void*)xp16, wih_cat, bih_a, bih_b, xw_cat16, (const f16*)nullptr);
    hipLaunchKernelGGL(rnn_kernel, dim3(256), dim3(768), 0, stream,
                       xw_cat16, whha16, whhb16, bhh_a, bhh_b, Wa, xb16, scores);
    hipLaunchKernelGGL((gemm_kernel<256, 256, 2, false, (1 << 30)>), dim3(512, 2), dim3(256), 0, stream,
                       (const void*)xb16, wb16, bb, bb, v16, xp16);
    hipLaunchKernelGGL(attn_kernel, dim3(128, 2), dim3(128), 0, stream, scores, v16, out);
}